// Round 4
// baseline (1170.339 us; speedup 1.0000x reference)
//
#include <hip/hip_runtime.h>
#include <hip/hip_bf16.h>
#include <math.h>

typedef __bf16 bf16;
typedef __bf16 bf16x8 __attribute__((ext_vector_type(8)));
typedef float  f32x4  __attribute__((ext_vector_type(4)));
typedef float  f32x4e __attribute__((ext_vector_type(4)));

#define MT     64     // triplets per block
#define ROWPAD 232    // LDS A-tile row stride in bf16 (464B -> only 2-way bank alias, free)
#define NREP   32     // replicated stat buffers to spread atomics

union PK8 { bf16 h[8]; uint4 u; };
union PKH { _Float16 h[2]; unsigned int u; };

__device__ inline uint4 pack8(const float4 a, const float4 b) {
  PK8 p;
  p.h[0] = (bf16)a.x; p.h[1] = (bf16)a.y; p.h[2] = (bf16)a.z; p.h[3] = (bf16)a.w;
  p.h[4] = (bf16)b.x; p.h[5] = (bf16)b.y; p.h[6] = (bf16)b.z; p.h[7] = (bf16)b.w;
  return p.u;
}

__device__ inline bf16x8 zero_bf16x8() {
  PK8 z; z.u = make_uint4(0u, 0u, 0u, 0u);
  return *(bf16x8*)z.h;
}

// fast transcendentals (v_exp/v_log/v_rcp; abs error ~1e-7, fine at this tolerance)
__device__ inline float fsigmoid(float x) {
  return __builtin_amdgcn_rcpf(1.f + __expf(-x));
}
__device__ inline float fsoftplus(float x) {
  return (x > 20.f) ? x : __logf(1.f + __expf(x));
}

// ---- pre-pass: fp32 -> bf16 table conversion (streamed once) ----
__global__ __launch_bounds__(256)
void k_cvt(const float* __restrict__ src, bf16* __restrict__ dst, long n8) {
  const long i = (long)blockIdx.x * 256 + threadIdx.x;
  if (i >= n8) return;
  const f32x4e a = __builtin_nontemporal_load((const f32x4e*)(src + i * 8));
  const f32x4e b = __builtin_nontemporal_load((const f32x4e*)(src + i * 8 + 4));
  PK8 p;
#pragma unroll
  for (int j = 0; j < 4; ++j) { p.h[j] = (bf16)a[j]; p.h[4 + j] = (bf16)b[j]; }
  *(uint4*)(dst + i * 8) = p.u;
}

// fc_w (128x208 fp32) -> (128x224 bf16, zero-padded K)
__global__ __launch_bounds__(256)
void k_cvtw(const float* __restrict__ fc_w, bf16* __restrict__ dst) {
  const int i = blockIdx.x * 256 + threadIdx.x;
  if (i >= 128 * 28) return;
  const int row = i / 28, c = i - row * 28;
  uint4 v;
  if (c < 26) {
    const float4* p = (const float4*)(fc_w + (size_t)row * 208 + c * 8);
    v = pack8(p[0], p[1]);
  } else {
    v = make_uint4(0u, 0u, 0u, 0u);
  }
  *(uint4*)(dst + (size_t)row * 224 + c * 8) = v;
}

// ---- counting-sort build: centre/cw + per-atom histogram ----
__global__ __launch_bounds__(256)
void k_prep(const int* __restrict__ trip_e1, const int* __restrict__ trip_e2,
            const int* __restrict__ eidx_dst, const float* __restrict__ cutoff_w,
            int* __restrict__ centre, float* __restrict__ cwbuf,
            int* __restrict__ cnt, int T) {
  for (int t = blockIdx.x * 256 + threadIdx.x; t < T; t += gridDim.x * 256) {
    const int e1 = trip_e1[t];
    const int e2 = trip_e2[t];
    const int ca = eidx_dst[e1];
    centre[t] = ca;
    cwbuf[t] = cutoff_w[e1] * cutoff_w[e2];
    atomicAdd(cnt + ca, 1);
  }
}

// exclusive prefix sum of cnt[0..N) -> off[0..N]; also seed cursors cnt2 = off.
__global__ __launch_bounds__(1024)
void k_scan(const int* __restrict__ cnt, int* __restrict__ off,
            int* __restrict__ cnt2, int N) {
  __shared__ int part[1024];
  const int tid = threadIdx.x;
  const int CH  = (N + 1023) >> 10;
  const int base = tid * CH;
  int s = 0;
  for (int i = 0; i < CH; ++i) {
    const int idx = base + i;
    if (idx < N) s += cnt[idx];
  }
  part[tid] = s;
  __syncthreads();
  for (int d = 1; d < 1024; d <<= 1) {
    const int v = part[tid];
    const int w = (tid >= d) ? part[tid - d] : 0;
    __syncthreads();
    part[tid] = v + w;
    __syncthreads();
  }
  int run = (tid == 0) ? 0 : part[tid - 1];
  for (int i = 0; i < CH; ++i) {
    const int idx = base + i;
    if (idx < N) {
      const int c = cnt[idx];
      off[idx] = run;
      cnt2[idx] = run;
      run += c;
    }
  }
  if (tid == 1023) off[N] = run;   // = T
}

// rank each triplet within its atom group; permute cw into sorted order.
__global__ __launch_bounds__(256)
void k_scatter(const int* __restrict__ centre, const float* __restrict__ cwbuf,
               int* __restrict__ cnt2, int* __restrict__ post,
               float* __restrict__ cw_s, int T) {
  for (int t = blockIdx.x * 256 + threadIdx.x; t < T; t += gridDim.x * 256) {
    const int c = centre[t];
    const int p = atomicAdd(cnt2 + c, 1);
    post[t] = p;
    cw_s[p] = cwbuf[t];
  }
}

// Single gather+GEMM pass:
//   z = concat-feats @ W^T + b  -> stored fp16-packed to zbuf row post[t] (centre-sorted)
//   per-column sum/sumsq (exact fp32) accumulated into replicated stat buffers
template<bool PRE>
__global__ __launch_bounds__(256)
void k_gemm(const float* __restrict__ atom_fea,  // (N,64) fp32
            const float* __restrict__ edge_fea,  // (E,64) fp32
            const bf16*  __restrict__ atom_bf,   // (N,64) bf16
            const bf16*  __restrict__ edge_bf,   // (E,64) bf16
            const float* __restrict__ r_ij,      // (E,3)
            const float* __restrict__ dist,      // (E,)
            const float* __restrict__ fc_w,      // (128,208) fp32 row-major
            const bf16*  __restrict__ fcw_bf,    // (128,224) bf16 row-major
            const float* __restrict__ fc_b,      // (128,)
            const int*  __restrict__ trip_e1,    // (T,)
            const int*  __restrict__ trip_e2,    // (T,)
            const int*  __restrict__ centre,     // (T,) precomputed (sequential read)
            const int*  __restrict__ post,       // (T,) sorted row index
            float* __restrict__ stat1,           // [NREP][256] (sum | sumsq)
            unsigned int* __restrict__ zbuf)     // [T][64] packed fp16 pairs, sorted rows
{
  __shared__ __align__(16) bf16 smA[MT * ROWPAD];   // 29696 B
  __shared__ int sPos[MT];

  const int tid  = threadIdx.x;
  const int lane = tid & 63;
  const int wv   = tid >> 6;      // wave 0..3, owns output cols [32w, 32w+32)
  const int quad = lane >> 4;     // 0..3
  const int l16  = lane & 15;
  const int t0   = blockIdx.x * MT;

  // ---- B fragments + bias, in registers ----
  bf16x8 bfrag[2][7];
  float  bias_v[2];
#pragma unroll
  for (int ns = 0; ns < 2; ++ns) {
    const int col = wv * 32 + ns * 16 + l16;
    bias_v[ns] = fc_b[col];
#pragma unroll
    for (int kc = 0; kc < 7; ++kc) {
      if (PRE) {
        bfrag[ns][kc] = *(const bf16x8*)(fcw_bf + (size_t)col * 224 + kc * 32 + quad * 8);
      } else {
        const int k0 = kc * 32 + quad * 8;
        if (k0 < 208) {
          const float4* p = (const float4*)(fc_w + (size_t)col * 208 + k0);
          PK8 pk; pk.u = pack8(p[0], p[1]);
          bfrag[ns][kc] = *(bf16x8*)pk.h;
        } else {
          bfrag[ns][kc] = zero_bf16x8();
        }
      }
    }
  }

  // ---- stage A tile: 64 rows x 224 bf16 (208 data + 16 zero pad) ----
  if (PRE) {
    // 4 threads per row; indices loaded once; 6 independent 16B gathers in flight.
    const int row = tid >> 2;
    const int cq  = tid & 3;
    const int t   = t0 + row;
    const int e1  = trip_e1[t];
    const int e2  = trip_e2[t];
    const int ca  = centre[t];
    const bf16* ar = atom_bf + (size_t)ca * 64;
    const bf16* r1 = edge_bf + (size_t)e1 * 64;
    const bf16* r2 = edge_bf + (size_t)e2 * 64;
    const uint4 v0 = *(const uint4*)(ar + cq * 8);
    const uint4 v1 = *(const uint4*)(ar + (cq + 4) * 8);
    const uint4 v2 = *(const uint4*)(r1 + cq * 8);
    const uint4 v3 = *(const uint4*)(r1 + (cq + 4) * 8);
    const uint4 v4 = *(const uint4*)(r2 + cq * 8);
    const uint4 v5 = *(const uint4*)(r2 + (cq + 4) * 8);
    bf16* dstr = smA + row * ROWPAD;
    if (cq == 0) {
      const float x1 = r_ij[e1 * 3], y1 = r_ij[e1 * 3 + 1], z1 = r_ij[e1 * 3 + 2];
      const float x2 = r_ij[e2 * 3], y2 = r_ij[e2 * 3 + 1], z2 = r_ij[e2 * 3 + 2];
      const float d1 = fmaxf(dist[e1], 1e-8f);
      const float d2 = fmaxf(dist[e2], 1e-8f);
      float cv = (x1 * x2 + y1 * y2 + z1 * z2) / (d1 * d2);
      cv = fminf(1.f, fmaxf(-1.f, cv));
      PK8 pa, pb;
#pragma unroll
      for (int j = 0; j < 8; ++j) {
        const float ca0 = cv - (-1.f + (float)j * (2.f / 15.f));
        const float ca1 = cv - (-1.f + (float)(j + 8) * (2.f / 15.f));
        pa.h[j] = (bf16)__expf(-(ca0 * ca0) * 44.4444444f); // 1/0.15^2
        pb.h[j] = (bf16)__expf(-(ca1 * ca1) * 44.4444444f);
      }
      *(uint4*)(dstr + 24 * 8) = pa.u;
      *(uint4*)(dstr + 25 * 8) = pb.u;
      sPos[row] = post[t];
    } else if (cq == 2) {
      *(uint4*)(dstr + 26 * 8) = make_uint4(0u, 0u, 0u, 0u);  // K pad
    } else if (cq == 3) {
      *(uint4*)(dstr + 27 * 8) = make_uint4(0u, 0u, 0u, 0u);  // K pad
    }
    *(uint4*)(dstr + cq * 8)        = v0;
    *(uint4*)(dstr + (cq + 4) * 8)  = v1;
    *(uint4*)(dstr + (cq + 8) * 8)  = v2;
    *(uint4*)(dstr + (cq + 12) * 8) = v3;
    *(uint4*)(dstr + (cq + 16) * 8) = v4;
    *(uint4*)(dstr + (cq + 20) * 8) = v5;
  } else {
    // fallback: gather from fp32 sources
    for (int i = tid; i < MT * 28; i += 256) {
      const int row = i / 28;
      const int c   = i - row * 28;
      const int t   = t0 + row;
      uint4 val;
      if (c < 8) {
        const int ca = centre[t];
        const float4* p = (const float4*)(atom_fea + (size_t)ca * 64 + c * 8);
        val = pack8(p[0], p[1]);
        if (c == 0) sPos[row] = post[t];
      } else if (c < 16) {
        const int e1 = trip_e1[t];
        const float4* p = (const float4*)(edge_fea + (size_t)e1 * 64 + (c - 8) * 8);
        val = pack8(p[0], p[1]);
      } else if (c < 24) {
        const int e2 = trip_e2[t];
        const float4* p = (const float4*)(edge_fea + (size_t)e2 * 64 + (c - 16) * 8);
        val = pack8(p[0], p[1]);
      } else if (c < 26) {
        const int e1 = trip_e1[t];
        const int e2 = trip_e2[t];
        const float x1 = r_ij[e1 * 3], y1 = r_ij[e1 * 3 + 1], z1 = r_ij[e1 * 3 + 2];
        const float x2 = r_ij[e2 * 3], y2 = r_ij[e2 * 3 + 1], z2 = r_ij[e2 * 3 + 2];
        const float d1 = fmaxf(dist[e1], 1e-8f);
        const float d2 = fmaxf(dist[e2], 1e-8f);
        float cv = (x1 * x2 + y1 * y2 + z1 * z2) / (d1 * d2);
        cv = fminf(1.f, fmaxf(-1.f, cv));
        PK8 p;
        const int b0 = (c - 24) * 8;
#pragma unroll
        for (int j = 0; j < 8; ++j) {
          const float ctr = -1.f + (float)(b0 + j) * (2.f / 15.f);
          const float dd = cv - ctr;
          p.h[j] = (bf16)__expf(-(dd * dd) * 44.4444444f);
        }
        val = p.u;
      } else {
        val = make_uint4(0u, 0u, 0u, 0u);
      }
      *(uint4*)(smA + row * ROWPAD + c * 8) = val;
    }
  }
  __syncthreads();

  // ---- MFMA: 64 rows x 32 cols per wave, K=224 ----
  f32x4 acc[4][2] = {};
#pragma unroll
  for (int kc = 0; kc < 7; ++kc) {
    bf16x8 afr[4];
#pragma unroll
    for (int ms = 0; ms < 4; ++ms)
      afr[ms] = *(const bf16x8*)(smA + (ms * 16 + l16) * ROWPAD + kc * 32 + quad * 8);
#pragma unroll
    for (int ms = 0; ms < 4; ++ms)
#pragma unroll
      for (int ns = 0; ns < 2; ++ns)
        acc[ms][ns] = __builtin_amdgcn_mfma_f32_16x16x32_bf16(afr[ms], bfrag[ns][kc], acc[ms][ns], 0, 0, 0);
  }
  // C/D layout: col = lane&15 (+16*ns+32*wv), row = quad*4 + r (+16*ms)

  // ---- store z as packed fp16 pairs to sorted row sPos[row] ----
  // ---- + per-column sum/sumsq (exact fp32) -> replicated atomics ----
  float s0 = 0.f, s20 = 0.f, s1 = 0.f, s21 = 0.f;
#pragma unroll
  for (int ms = 0; ms < 4; ++ms)
#pragma unroll
    for (int r = 0; r < 4; ++r) {
      const float z0 = acc[ms][0][r] + bias_v[0];
      const float z1 = acc[ms][1][r] + bias_v[1];
      PKH pk; pk.h[0] = (_Float16)z0; pk.h[1] = (_Float16)z1;
      const int row = ms * 16 + quad * 4 + r;
      __builtin_nontemporal_store(pk.u, zbuf + (size_t)sPos[row] * 64 + wv * 16 + l16);
      s0 += z0; s20 += z0 * z0; s1 += z1; s21 += z1 * z1;
    }
  s0  += __shfl_xor(s0, 16);  s0  += __shfl_xor(s0, 32);
  s20 += __shfl_xor(s20, 16); s20 += __shfl_xor(s20, 32);
  s1  += __shfl_xor(s1, 16);  s1  += __shfl_xor(s1, 32);
  s21 += __shfl_xor(s21, 16); s21 += __shfl_xor(s21, 32);
  if (quad == 0) {
    float* sb = stat1 + (size_t)(blockIdx.x & (NREP - 1)) * 256;
    const int c0 = wv * 32 + l16;
    atomicAdd(sb + c0, s0);
    atomicAdd(sb + 128 + c0, s20);
    atomicAdd(sb + c0 + 16, s1);
    atomicAdd(sb + 128 + c0 + 16, s21);
  }
}

__global__ void k_fin1(const float* __restrict__ stat1,
                       const float* __restrict__ g1, const float* __restrict__ b1,
                       float* __restrict__ bn1sc, float* __restrict__ bn1sh, float invT) {
  const int j = threadIdx.x; // 128
  float s = 0.f, s2 = 0.f;
  for (int r = 0; r < NREP; ++r) { s += stat1[r * 256 + j]; s2 += stat1[r * 256 + 128 + j]; }
  const float mu  = s * invT;
  const float var = fmaxf(s2 * invT - mu * mu, 0.f);
  const float sc  = g1[j] * rsqrtf(var + 1e-5f);
  bn1sc[j] = sc;
  bn1sh[j] = b1[j] - mu * sc;
}

// Gather-apply: one wave per atom, sequential z rows, register accumulate, NO atomics.
__global__ __launch_bounds__(256)
void k_apply2(const unsigned int* __restrict__ zbuf,  // [T][64] packed, centre-sorted
              const int*   __restrict__ off,          // [N+1]
              const float* __restrict__ cw_s,         // [T] sorted
              const float* __restrict__ bn1sc, const float* __restrict__ bn1sh,
              float* __restrict__ aggr, int N)
{
  const int n = (blockIdx.x << 2) | (threadIdx.x >> 6);
  if (n >= N) return;
  const int f   = threadIdx.x & 63;
  const int wg  = ((f >> 5) << 4) | (f & 15);
  const int sel = (f >> 4) & 1;
  const float scg = bn1sc[f],      shg = bn1sh[f];
  const float scc = bn1sc[64 + f], shc = bn1sh[64 + f];
  const int i0 = off[n], i1 = off[n + 1];
  float acc = 0.f;
  for (int i = i0; i < i1; ++i) {
    const unsigned int ug = __builtin_nontemporal_load(zbuf + (size_t)i * 64 + wg);
    const unsigned int uc = __builtin_nontemporal_load(zbuf + (size_t)i * 64 + 32 + wg);
    PKH a, b; a.u = ug; b.u = uc;
    const float zg = (sel ? (float)a.h[1] : (float)a.h[0]) * scg + shg;
    const float zc = (sel ? (float)b.h[1] : (float)b.h[0]) * scc + shc;
    acc += fsigmoid(zg) * fsoftplus(zc) * cw_s[i];
  }
  aggr[(size_t)n * 64 + f] = acc;
}

__global__ __launch_bounds__(256)
void k_bn2stats(const float* __restrict__ aggr, float* __restrict__ stat2, int N) {
  const int col = threadIdx.x & 63;
  const int rg  = threadIdx.x >> 6;
  float s = 0.f, s2 = 0.f;
  for (int n = blockIdx.x * 4 + rg; n < N; n += gridDim.x * 4) {
    const float v = aggr[(size_t)n * 64 + col];
    s += v; s2 += v * v;
  }
  __shared__ float ps[4][64], ps2[4][64];
  ps[rg][col] = s; ps2[rg][col] = s2;
  __syncthreads();
  if (rg == 0) {
    s  = ps[0][col] + ps[1][col] + ps[2][col] + ps[3][col];
    s2 = ps2[0][col] + ps2[1][col] + ps2[2][col] + ps2[3][col];
    atomicAdd(stat2 + col, s);
    atomicAdd(stat2 + 64 + col, s2);
  }
}

__global__ __launch_bounds__(256)
void k_final(const float* __restrict__ aggr, const float* __restrict__ atom,
             const float* __restrict__ stat2,
             const float* __restrict__ g2, const float* __restrict__ b2,
             float* __restrict__ out, int total, float invN) {
  const int idx = blockIdx.x * 256 + threadIdx.x;
  if (idx >= total) return;
  const int col = idx & 63;
  const float mu  = stat2[col] * invN;
  const float var = fmaxf(stat2[64 + col] * invN - mu * mu, 0.f);
  const float sc  = g2[col] * rsqrtf(var + 1e-5f);
  const float sh  = b2[col] - mu * sc;
  const float x   = aggr[idx] * sc + sh + atom[idx];
  out[idx] = fsoftplus(x);
}

extern "C" void kernel_launch(void* const* d_in, const int* in_sizes, int n_in,
                              void* d_out, int out_size, void* d_ws, size_t ws_size,
                              hipStream_t stream) {
  const float* atom_fea = (const float*)d_in[0];
  const float* edge_fea = (const float*)d_in[1];
  const float* r_ij     = (const float*)d_in[2];
  const float* dist     = (const float*)d_in[3];
  const float* cutoff_w = (const float*)d_in[4];
  const float* fc_w     = (const float*)d_in[5];
  const float* fc_b     = (const float*)d_in[6];
  const float* bn1g     = (const float*)d_in[7];
  const float* bn1b     = (const float*)d_in[8];
  const float* bn2g     = (const float*)d_in[9];
  const float* bn2b     = (const float*)d_in[10];
  const int*  eidx      = (const int*)d_in[11];  // (2,E)
  const int*  tidx      = (const int*)d_in[12];  // (2,T)

  const int N = in_sizes[0] / 64;
  const int E = in_sizes[3];
  const int T = in_sizes[12] / 2;   // 1,000,000 -> divisible by MT=64

  size_t off_b = 0;
  char* base = (char*)d_ws;
  auto carve = [&](size_t bytes) -> void* {
    void* p = base + off_b;
    off_b += (bytes + 255) & ~(size_t)255;
    return p;
  };
  float* aggr    = (float*)carve((size_t)N * 64 * 4);
  float* stat1   = (float*)carve((size_t)NREP * 256 * 4);
  float* bn1sc   = (float*)carve(128 * 4);
  float* bn1sh   = (float*)carve(128 * 4);
  float* stat2   = (float*)carve(128 * 4);
  int*   cnt     = (int*)carve((size_t)N * 4);
  int*   offs    = (int*)carve((size_t)(N + 1) * 4);
  int*   cnt2    = (int*)carve((size_t)N * 4);
  int*   centre  = (int*)carve((size_t)T * 4);
  float* cwbuf   = (float*)carve((size_t)T * 4);
  int*   post    = (int*)carve((size_t)T * 4);
  float* cw_s    = (float*)carve((size_t)T * 4);
  unsigned int* zbuf = (unsigned int*)carve((size_t)T * 64 * 4); // packed fp16 pairs (256MB)
  bf16*  edge_bf = (bf16*)carve((size_t)E * 64 * 2);
  bf16*  atom_bf = (bf16*)carve((size_t)N * 64 * 2);
  bf16*  fcw_bf  = (bf16*)carve((size_t)128 * 224 * 2);
  const bool pre = (off_b <= ws_size);

  hipMemsetAsync(cnt,   0, (size_t)N * 4, stream);
  hipMemsetAsync(stat1, 0, (size_t)NREP * 256 * sizeof(float), stream);
  hipMemsetAsync(stat2, 0, 128 * sizeof(float), stream);

  const int nblk = T / MT;
  if (pre) {
    const long e8 = (long)E * 64 / 8;
    const long a8 = (long)N * 64 / 8;
    k_cvt<<<(int)((e8 + 255) / 256), 256, 0, stream>>>(edge_fea, edge_bf, e8);
    k_cvt<<<(int)((a8 + 255) / 256), 256, 0, stream>>>(atom_fea, atom_bf, a8);
    k_cvtw<<<14, 256, 0, stream>>>(fc_w, fcw_bf);
  }
  k_prep<<<2048, 256, 0, stream>>>(tidx, tidx + T, eidx + E, cutoff_w,
                                   centre, cwbuf, cnt, T);
  k_scan<<<1, 1024, 0, stream>>>(cnt, offs, cnt2, N);
  k_scatter<<<2048, 256, 0, stream>>>(centre, cwbuf, cnt2, post, cw_s, T);
  if (pre) {
    k_gemm<true><<<nblk, 256, 0, stream>>>(atom_fea, edge_fea, atom_bf, edge_bf,
                                           r_ij, dist, fc_w, fcw_bf, fc_b,
                                           tidx, tidx + T, centre, post,
                                           stat1, zbuf);
  } else {
    k_gemm<false><<<nblk, 256, 0, stream>>>(atom_fea, edge_fea, atom_bf, edge_bf,
                                            r_ij, dist, fc_w, fcw_bf, fc_b,
                                            tidx, tidx + T, centre, post,
                                            stat1, zbuf);
  }
  k_fin1<<<1, 128, 0, stream>>>(stat1, bn1g, bn1b, bn1sc, bn1sh, 1.0f / (float)T);
  k_apply2<<<(N + 3) / 4, 256, 0, stream>>>(zbuf, offs, cw_s, bn1sc, bn1sh, aggr, N);
  k_bn2stats<<<256, 256, 0, stream>>>(aggr, stat2, N);
  const int total = N * 64;
  k_final<<<(total + 255) / 256, 256, 0, stream>>>(aggr, atom_fea, stat2, bn2g, bn2b,
                                                   (float*)d_out, total, 1.0f / (float)N);
}

// Round 5
// 1054.615 us; speedup vs baseline: 1.1097x; 1.1097x over previous
//
#include <hip/hip_runtime.h>
#include <hip/hip_bf16.h>
#include <math.h>

typedef __bf16 bf16;
typedef __bf16 bf16x8 __attribute__((ext_vector_type(8)));
typedef float  f32x4  __attribute__((ext_vector_type(4)));
typedef float  f32x4e __attribute__((ext_vector_type(4)));

#define MT     64     // triplets per block
#define ROWPAD 232    // LDS A-tile row stride in bf16 (464B -> only 2-way bank alias, free)
#define NREP   32     // replicated stat buffers to spread atomics

union PK8 { bf16 h[8]; uint4 u; };
union PKH { _Float16 h[2]; unsigned int u; };

__device__ inline uint4 pack8(const float4 a, const float4 b) {
  PK8 p;
  p.h[0] = (bf16)a.x; p.h[1] = (bf16)a.y; p.h[2] = (bf16)a.z; p.h[3] = (bf16)a.w;
  p.h[4] = (bf16)b.x; p.h[5] = (bf16)b.y; p.h[6] = (bf16)b.z; p.h[7] = (bf16)b.w;
  return p.u;
}

__device__ inline bf16x8 zero_bf16x8() {
  PK8 z; z.u = make_uint4(0u, 0u, 0u, 0u);
  return *(bf16x8*)z.h;
}

// fast transcendentals: v_exp/v_log/v_rcp based (abs err ~1e-7, vs 0.0625 tolerance).
// Replaces IEEE div sequence (~10 insts) and libm log1pf chain (the round-3
// k_apply VALUBusy=99% culprit).
__device__ inline float fsigmoid(float x) {
  return __builtin_amdgcn_rcpf(1.f + __expf(-x));
}
__device__ inline float fsoftplus(float x) {
  return (x > 20.f) ? x : __logf(1.f + __expf(x));
}

// ---- pre-pass: fp32 -> bf16 table conversion (streamed once) ----
// nontemporal loads: don't let the 410MB fp32 stream evict the bf16 table from L3.
__global__ __launch_bounds__(256)
void k_cvt(const float* __restrict__ src, bf16* __restrict__ dst, long n8) {
  const long i = (long)blockIdx.x * 256 + threadIdx.x;
  if (i >= n8) return;
  const f32x4e a = __builtin_nontemporal_load((const f32x4e*)(src + i * 8));
  const f32x4e b = __builtin_nontemporal_load((const f32x4e*)(src + i * 8 + 4));
  PK8 p;
#pragma unroll
  for (int j = 0; j < 4; ++j) { p.h[j] = (bf16)a[j]; p.h[4 + j] = (bf16)b[j]; }
  *(uint4*)(dst + i * 8) = p.u;
}

// fc_w (128x208 fp32) -> (128x224 bf16, zero-padded K)
__global__ __launch_bounds__(256)
void k_cvtw(const float* __restrict__ fc_w, bf16* __restrict__ dst) {
  const int i = blockIdx.x * 256 + threadIdx.x;
  if (i >= 128 * 28) return;
  const int row = i / 28, c = i - row * 28;
  uint4 v;
  if (c < 26) {
    const float4* p = (const float4*)(fc_w + (size_t)row * 208 + c * 8);
    v = pack8(p[0], p[1]);
  } else {
    v = make_uint4(0u, 0u, 0u, 0u);
  }
  *(uint4*)(dst + (size_t)row * 224 + c * 8) = v;
}

// Single gather+GEMM pass:
//   z = concat-feats @ W^T + b  -> stored fp16-packed (T x 64 words, swizzled) to workspace
//   per-column sum/sumsq (exact fp32) accumulated into replicated stat buffers
//   centre[t], cw[t] side-stored for the apply pass.
template<bool PRE>
__global__ __launch_bounds__(256)
void k_gemm(const float* __restrict__ atom_fea,  // (N,64) fp32
            const float* __restrict__ edge_fea,  // (E,64) fp32
            const bf16*  __restrict__ atom_bf,   // (N,64) bf16
            const bf16*  __restrict__ edge_bf,   // (E,64) bf16
            const float* __restrict__ r_ij,      // (E,3)
            const float* __restrict__ dist,      // (E,)
            const float* __restrict__ cutoff_w,  // (E,)
            const float* __restrict__ fc_w,      // (128,208) fp32 row-major
            const bf16*  __restrict__ fcw_bf,    // (128,224) bf16 row-major
            const float* __restrict__ fc_b,      // (128,)
            const int*  __restrict__ eidx_dst,   // edge_index[1] (E,)
            const int*  __restrict__ trip_e1,    // (T,)
            const int*  __restrict__ trip_e2,    // (T,)
            float* __restrict__ stat1,           // [NREP][256] (sum | sumsq)
            unsigned int* __restrict__ zbuf,     // [T][64] packed fp16 pairs
            int*   __restrict__ centre,          // [T]
            float* __restrict__ cwbuf)           // [T]
{
  __shared__ __align__(16) bf16 smA[MT * ROWPAD];   // 29696 B

  const int tid  = threadIdx.x;
  const int lane = tid & 63;
  const int wv   = tid >> 6;      // wave 0..3, owns output cols [32w, 32w+32)
  const int quad = lane >> 4;     // 0..3
  const int l16  = lane & 15;
  const int t0   = blockIdx.x * MT;

  // ---- B fragments + bias, in registers ----
  bf16x8 bfrag[2][7];
  float  bias_v[2];
#pragma unroll
  for (int ns = 0; ns < 2; ++ns) {
    const int col = wv * 32 + ns * 16 + l16;
    bias_v[ns] = fc_b[col];
#pragma unroll
    for (int kc = 0; kc < 7; ++kc) {
      if (PRE) {
        bfrag[ns][kc] = *(const bf16x8*)(fcw_bf + (size_t)col * 224 + kc * 32 + quad * 8);
      } else {
        const int k0 = kc * 32 + quad * 8;
        if (k0 < 208) {
          const float4* p = (const float4*)(fc_w + (size_t)col * 208 + k0);
          PK8 pk; pk.u = pack8(p[0], p[1]);
          bfrag[ns][kc] = *(bf16x8*)pk.h;
        } else {
          bfrag[ns][kc] = zero_bf16x8();
        }
      }
    }
  }

  // ---- stage A tile: 64 rows x 224 bf16 (208 data + 16 zero pad) ----
  if (PRE) {
    // 4 threads per row; each owns data chunks {cq, cq+4, ..., cq+20}.
    // Indices loaded ONCE, then 6 independent 16B gathers all in flight.
    // Angle computed ONCE per row (cq==0) to avoid duplicate random r_ij/dist gathers.
    const int row = tid >> 2;
    const int cq  = tid & 3;
    const int t   = t0 + row;
    const int e1  = trip_e1[t];
    const int e2  = trip_e2[t];
    const int ca  = eidx_dst[e1];
    const bf16* ar = atom_bf + (size_t)ca * 64;
    const bf16* r1 = edge_bf + (size_t)e1 * 64;
    const bf16* r2 = edge_bf + (size_t)e2 * 64;
    const uint4 v0 = *(const uint4*)(ar + cq * 8);
    const uint4 v1 = *(const uint4*)(ar + (cq + 4) * 8);
    const uint4 v2 = *(const uint4*)(r1 + cq * 8);
    const uint4 v3 = *(const uint4*)(r1 + (cq + 4) * 8);
    const uint4 v4 = *(const uint4*)(r2 + cq * 8);
    const uint4 v5 = *(const uint4*)(r2 + (cq + 4) * 8);
    bf16* dstr = smA + row * ROWPAD;
    if (cq == 0) {
      const float x1 = r_ij[e1 * 3], y1 = r_ij[e1 * 3 + 1], z1 = r_ij[e1 * 3 + 2];
      const float x2 = r_ij[e2 * 3], y2 = r_ij[e2 * 3 + 1], z2 = r_ij[e2 * 3 + 2];
      const float d1 = fmaxf(dist[e1], 1e-8f);
      const float d2 = fmaxf(dist[e2], 1e-8f);
      float cv = (x1 * x2 + y1 * y2 + z1 * z2) / (d1 * d2);
      cv = fminf(1.f, fmaxf(-1.f, cv));
      PK8 pa, pb;
#pragma unroll
      for (int j = 0; j < 8; ++j) {
        const float ca0 = cv - (-1.f + (float)j * (2.f / 15.f));
        const float ca1 = cv - (-1.f + (float)(j + 8) * (2.f / 15.f));
        pa.h[j] = (bf16)__expf(-(ca0 * ca0) * 44.4444444f); // 1/0.15^2
        pb.h[j] = (bf16)__expf(-(ca1 * ca1) * 44.4444444f);
      }
      *(uint4*)(dstr + 24 * 8) = pa.u;
      *(uint4*)(dstr + 25 * 8) = pb.u;
      centre[t] = ca;
      cwbuf[t] = cutoff_w[e1] * cutoff_w[e2];
    } else if (cq == 2) {
      *(uint4*)(dstr + 26 * 8) = make_uint4(0u, 0u, 0u, 0u);  // K pad
    } else if (cq == 3) {
      *(uint4*)(dstr + 27 * 8) = make_uint4(0u, 0u, 0u, 0u);  // K pad
    }
    *(uint4*)(dstr + cq * 8)        = v0;
    *(uint4*)(dstr + (cq + 4) * 8)  = v1;
    *(uint4*)(dstr + (cq + 8) * 8)  = v2;
    *(uint4*)(dstr + (cq + 12) * 8) = v3;
    *(uint4*)(dstr + (cq + 16) * 8) = v4;
    *(uint4*)(dstr + (cq + 20) * 8) = v5;
  } else {
    // fallback: gather from fp32 sources
    for (int i = tid; i < MT * 28; i += 256) {
      const int row = i / 28;
      const int c   = i - row * 28;
      const int t   = t0 + row;
      uint4 val;
      if (c < 8) {
        const int e1 = trip_e1[t];
        const int ca = eidx_dst[e1];
        const float4* p = (const float4*)(atom_fea + (size_t)ca * 64 + c * 8);
        val = pack8(p[0], p[1]);
        if (c == 0) {
          const int e2 = trip_e2[t];
          centre[t] = ca;
          cwbuf[t] = cutoff_w[e1] * cutoff_w[e2];
        }
      } else if (c < 16) {
        const int e1 = trip_e1[t];
        const float4* p = (const float4*)(edge_fea + (size_t)e1 * 64 + (c - 8) * 8);
        val = pack8(p[0], p[1]);
      } else if (c < 24) {
        const int e2 = trip_e2[t];
        const float4* p = (const float4*)(edge_fea + (size_t)e2 * 64 + (c - 16) * 8);
        val = pack8(p[0], p[1]);
      } else if (c < 26) {
        const int e1 = trip_e1[t];
        const int e2 = trip_e2[t];
        const float x1 = r_ij[e1 * 3], y1 = r_ij[e1 * 3 + 1], z1 = r_ij[e1 * 3 + 2];
        const float x2 = r_ij[e2 * 3], y2 = r_ij[e2 * 3 + 1], z2 = r_ij[e2 * 3 + 2];
        const float d1 = fmaxf(dist[e1], 1e-8f);
        const float d2 = fmaxf(dist[e2], 1e-8f);
        float cv = (x1 * x2 + y1 * y2 + z1 * z2) / (d1 * d2);
        cv = fminf(1.f, fmaxf(-1.f, cv));
        PK8 p;
        const int b0 = (c - 24) * 8;
#pragma unroll
        for (int j = 0; j < 8; ++j) {
          const float ctr = -1.f + (float)(b0 + j) * (2.f / 15.f);
          const float dd = cv - ctr;
          p.h[j] = (bf16)__expf(-(dd * dd) * 44.4444444f);
        }
        val = p.u;
      } else {
        val = make_uint4(0u, 0u, 0u, 0u);
      }
      *(uint4*)(smA + row * ROWPAD + c * 8) = val;
    }
  }
  __syncthreads();

  // ---- MFMA: 64 rows x 32 cols per wave, K=224 ----
  f32x4 acc[4][2] = {};
#pragma unroll
  for (int kc = 0; kc < 7; ++kc) {
    bf16x8 afr[4];
#pragma unroll
    for (int ms = 0; ms < 4; ++ms)
      afr[ms] = *(const bf16x8*)(smA + (ms * 16 + l16) * ROWPAD + kc * 32 + quad * 8);
#pragma unroll
    for (int ms = 0; ms < 4; ++ms)
#pragma unroll
      for (int ns = 0; ns < 2; ++ns)
        acc[ms][ns] = __builtin_amdgcn_mfma_f32_16x16x32_bf16(afr[ms], bfrag[ns][kc], acc[ms][ns], 0, 0, 0);
  }
  // C/D layout: col = lane&15 (+16*ns+32*wv), row = quad*4 + r (+16*ms)

  // ---- store z as packed fp16 pairs (swizzled: word wv*16+l16 = cols (c, c+16)) ----
  // ---- + per-column sum/sumsq (exact fp32) -> replicated atomics ----
  unsigned int* zw = zbuf + (size_t)t0 * 64;
  float s0 = 0.f, s20 = 0.f, s1 = 0.f, s21 = 0.f;
#pragma unroll
  for (int ms = 0; ms < 4; ++ms)
#pragma unroll
    for (int r = 0; r < 4; ++r) {
      const float z0 = acc[ms][0][r] + bias_v[0];
      const float z1 = acc[ms][1][r] + bias_v[1];
      PKH pk; pk.h[0] = (_Float16)z0; pk.h[1] = (_Float16)z1;
      const int row = ms * 16 + quad * 4 + r;
      __builtin_nontemporal_store(pk.u, zw + (size_t)row * 64 + wv * 16 + l16);
      s0 += z0; s20 += z0 * z0; s1 += z1; s21 += z1 * z1;
    }
  s0  += __shfl_xor(s0, 16);  s0  += __shfl_xor(s0, 32);
  s20 += __shfl_xor(s20, 16); s20 += __shfl_xor(s20, 32);
  s1  += __shfl_xor(s1, 16);  s1  += __shfl_xor(s1, 32);
  s21 += __shfl_xor(s21, 16); s21 += __shfl_xor(s21, 32);
  if (quad == 0) {
    float* sb = stat1 + (size_t)(blockIdx.x & (NREP - 1)) * 256;
    const int c0 = wv * 32 + l16;
    atomicAdd(sb + c0, s0);
    atomicAdd(sb + 128 + c0, s20);
    atomicAdd(sb + c0 + 16, s1);
    atomicAdd(sb + 128 + c0 + 16, s21);
  }
}

__global__ void k_fin1(const float* __restrict__ stat1,
                       const float* __restrict__ g1, const float* __restrict__ b1,
                       float* __restrict__ bn1sc, float* __restrict__ bn1sh, float invT) {
  const int j = threadIdx.x; // 128
  float s = 0.f, s2 = 0.f;
  for (int r = 0; r < NREP; ++r) { s += stat1[r * 256 + j]; s2 += stat1[r * 256 + 128 + j]; }
  const float mu  = s * invT;
  const float var = fmaxf(s2 * invT - mu * mu, 0.f);
  const float sc  = g1[j] * rsqrtf(var + 1e-5f);
  bn1sc[j] = sc;
  bn1sh[j] = b1[j] - mu * sc;
}

// Streaming apply: read packed fp16 z, BN1 affine, gate*core*cw (fast-math),
// scatter-add to aggr replica.
__global__ __launch_bounds__(256)
void k_apply(const unsigned int* __restrict__ zbuf, // [T][64] packed
             const int*   __restrict__ centre,      // [T]
             const float* __restrict__ cwbuf,       // [T]
             const float* __restrict__ bn1sc, const float* __restrict__ bn1sh,
             float* __restrict__ aggr, size_t repN, int T)
{
  const int lane = threadIdx.x & 63;
  const int sub  = threadIdx.x >> 6;   // 0..3 : triplet sub-index within block
  const int f    = lane;
  const int wg   = ((f >> 5) << 4) | (f & 15);
  const int sel  = (f >> 4) & 1;
  const float scg = bn1sc[f],      shg = bn1sh[f];
  const float scc = bn1sc[64 + f], shc = bn1sh[64 + f];
  float* ag = aggr + (size_t)(blockIdx.x & 1) * repN;
  for (int t = blockIdx.x * 4 + sub; t < T; t += gridDim.x * 4) {
    const unsigned int ug = __builtin_nontemporal_load(zbuf + (size_t)t * 64 + wg);
    const unsigned int uc = __builtin_nontemporal_load(zbuf + (size_t)t * 64 + 32 + wg);
    PKH a, b; a.u = ug; b.u = uc;
    const float zg = (sel ? (float)a.h[1] : (float)a.h[0]) * scg + shg;
    const float zc = (sel ? (float)b.h[1] : (float)b.h[0]) * scc + shc;
    atomicAdd(ag + (size_t)centre[t] * 64 + f, fsigmoid(zg) * fsoftplus(zc) * cwbuf[t]);
  }
}

// Fold the 2 aggr replicas (write combined back to replica 0) + BN2 stats.
__global__ __launch_bounds__(256)
void k_bn2stats(float* __restrict__ aggr, size_t repN, float* __restrict__ stat2, int N) {
  const int col = threadIdx.x & 63;
  const int rg  = threadIdx.x >> 6;
  float s = 0.f, s2 = 0.f;
  for (int n = blockIdx.x * 4 + rg; n < N; n += gridDim.x * 4) {
    const size_t idx = (size_t)n * 64 + col;
    const float v = aggr[idx] + aggr[repN + idx];
    aggr[idx] = v;
    s += v; s2 += v * v;
  }
  __shared__ float ps[4][64], ps2[4][64];
  ps[rg][col] = s; ps2[rg][col] = s2;
  __syncthreads();
  if (rg == 0) {
    s  = ps[0][col] + ps[1][col] + ps[2][col] + ps[3][col];
    s2 = ps2[0][col] + ps2[1][col] + ps2[2][col] + ps2[3][col];
    atomicAdd(stat2 + col, s);
    atomicAdd(stat2 + 64 + col, s2);
  }
}

__global__ __launch_bounds__(256)
void k_final(const float* __restrict__ aggr, const float* __restrict__ atom,
             const float* __restrict__ stat2,
             const float* __restrict__ g2, const float* __restrict__ b2,
             float* __restrict__ out, int total, float invN) {
  const int idx = blockIdx.x * 256 + threadIdx.x;
  if (idx >= total) return;
  const int col = idx & 63;
  const float mu  = stat2[col] * invN;
  const float var = fmaxf(stat2[64 + col] * invN - mu * mu, 0.f);
  const float sc  = g2[col] * rsqrtf(var + 1e-5f);
  const float sh  = b2[col] - mu * sc;
  const float x   = aggr[idx] * sc + sh + atom[idx];
  out[idx] = fsoftplus(x);
}

extern "C" void kernel_launch(void* const* d_in, const int* in_sizes, int n_in,
                              void* d_out, int out_size, void* d_ws, size_t ws_size,
                              hipStream_t stream) {
  const float* atom_fea = (const float*)d_in[0];
  const float* edge_fea = (const float*)d_in[1];
  const float* r_ij     = (const float*)d_in[2];
  const float* dist     = (const float*)d_in[3];
  const float* cutoff_w = (const float*)d_in[4];
  const float* fc_w     = (const float*)d_in[5];
  const float* fc_b     = (const float*)d_in[6];
  const float* bn1g     = (const float*)d_in[7];
  const float* bn1b     = (const float*)d_in[8];
  const float* bn2g     = (const float*)d_in[9];
  const float* bn2b     = (const float*)d_in[10];
  const int*  eidx      = (const int*)d_in[11];  // (2,E)
  const int*  tidx      = (const int*)d_in[12];  // (2,T)

  const int N = in_sizes[0] / 64;
  const int E = in_sizes[3];
  const int T = in_sizes[12] / 2;   // 1,000,000 -> divisible by MT=64

  const size_t repN = (size_t)N * 64;

  size_t off = 0;
  char* base = (char*)d_ws;
  auto carve = [&](size_t bytes) -> void* {
    void* p = base + off;
    off += (bytes + 255) & ~(size_t)255;
    return p;
  };
  float* aggr    = (float*)carve(2 * repN * 4);          // 2 replicas
  float* stat1   = (float*)carve((size_t)NREP * 256 * 4);
  float* bn1sc   = (float*)carve(128 * 4);
  float* bn1sh   = (float*)carve(128 * 4);
  float* stat2   = (float*)carve(128 * 4);
  float* cwbuf   = (float*)carve((size_t)T * 4);
  int*   centre  = (int*)carve((size_t)T * 4);
  unsigned int* zbuf = (unsigned int*)carve((size_t)T * 64 * 4); // packed fp16 pairs (256MB)
  bf16*  edge_bf = (bf16*)carve((size_t)E * 64 * 2);
  bf16*  atom_bf = (bf16*)carve((size_t)N * 64 * 2);
  bf16*  fcw_bf  = (bf16*)carve((size_t)128 * 224 * 2);
  const bool pre = (off <= ws_size);

  hipMemsetAsync(aggr,  0, 2 * repN * sizeof(float), stream);
  hipMemsetAsync(stat1, 0, (size_t)NREP * 256 * sizeof(float), stream);
  hipMemsetAsync(stat2, 0, 128 * sizeof(float), stream);

  const int nblk = T / MT;
  if (pre) {
    const long e8 = (long)E * 64 / 8;
    const long a8 = (long)N * 64 / 8;
    k_cvt<<<(int)((e8 + 255) / 256), 256, 0, stream>>>(edge_fea, edge_bf, e8);
    k_cvt<<<(int)((a8 + 255) / 256), 256, 0, stream>>>(atom_fea, atom_bf, a8);
    k_cvtw<<<14, 256, 0, stream>>>(fc_w, fcw_bf);
    k_gemm<true><<<nblk, 256, 0, stream>>>(atom_fea, edge_fea, atom_bf, edge_bf,
                                           r_ij, dist, cutoff_w, fc_w, fcw_bf, fc_b,
                                           eidx + E, tidx, tidx + T,
                                           stat1, zbuf, centre, cwbuf);
  } else {
    k_gemm<false><<<nblk, 256, 0, stream>>>(atom_fea, edge_fea, atom_bf, edge_bf,
                                            r_ij, dist, cutoff_w, fc_w, fcw_bf, fc_b,
                                            eidx + E, tidx, tidx + T,
                                            stat1, zbuf, centre, cwbuf);
  }
  k_fin1<<<1, 128, 0, stream>>>(stat1, bn1g, bn1b, bn1sc, bn1sh, 1.0f / (float)T);
  k_apply<<<4096, 256, 0, stream>>>(zbuf, centre, cwbuf, bn1sc, bn1sh, aggr, repN, T);
  k_bn2stats<<<256, 256, 0, stream>>>(aggr, repN, stat2, N);
  const int total = N * 64;
  k_final<<<(total + 255) / 256, 256, 0, stream>>>(aggr, atom_fea, stat2, bn2g, bn2b,
                                                   (float*)d_out, total, 1.0f / (float)N);
}